// Round 1
// baseline (219.538 us; speedup 1.0000x reference)
//
#include <hip/hip_runtime.h>
#include <math.h>

#define DIM   256
#define NLVL  5
#define NB1   1024   // pass1 blocks per level (4096 waves <= N, so every wave gets rows)

struct Ptrs {
  const float* p[NLVL];
  const float* W[NLVL];
  const float* b[NLVL];
};

// ---------------- pass 1: logits + per-(level,block) online-softmax partials ----
__global__ __launch_bounds__(256) void k_pass1(Ptrs pt, float* __restrict__ logits,
                                               float2* __restrict__ part, int N)
{
  const int lvl  = blockIdx.y;
  const float* __restrict__ p = pt.p[lvl];
  const int lane = threadIdx.x & 63;
  const int wid  = threadIdx.x >> 6;          // 0..3 (4 waves / block)
  const float4 wf  = *reinterpret_cast<const float4*>(pt.W[lvl] + lane * 4);
  const float bias = *pt.b[lvl];

  float m = -INFINITY, s = 0.f;
  const int gw = blockIdx.x * 4 + wid;
  const int nw = gridDim.x * 4;
  for (int n = gw; n < N; n += nw) {
    float4 pv = *reinterpret_cast<const float4*>(p + (size_t)n * DIM + lane * 4);
    float d = pv.x * wf.x + pv.y * wf.y + pv.z * wf.z + pv.w * wf.w;
    #pragma unroll
    for (int off = 32; off; off >>= 1) d += __shfl_xor(d, off);
    d += bias;                                 // all 64 lanes hold the logit
    if (lane == 0) logits[(size_t)lvl * N + n] = d;
    float Mn = fmaxf(m, d);                    // online softmax update
    s = s * __expf(m - Mn) + __expf(d - Mn);   // first iter: 0*exp(-inf)=0, +1
    m = Mn;
  }

  __shared__ float smM[4], smS[4];
  if (lane == 0) { smM[wid] = m; smS[wid] = s; }
  __syncthreads();
  if (threadIdx.x == 0) {
    float M = smM[0], S = smS[0];
    #pragma unroll
    for (int i = 1; i < 4; i++) {
      float mi = smM[i], si = smS[i];
      float Mn = fmaxf(M, mi);
      if (Mn > -INFINITY) {
        S = S * __expf(M - Mn) + si * __expf(mi - Mn);
        M = Mn;
      }
    }
    part[lvl * NB1 + blockIdx.x] = make_float2(M, S);
  }
}

// ---------------- pass 1b: combine partials -> per-level (M, S) -----------------
__global__ __launch_bounds__(320) void k_reduce(const float2* __restrict__ part,
                                                float2* __restrict__ stats)
{
  const int lvl  = threadIdx.x >> 6;           // 5 waves, one per level
  const int lane = threadIdx.x & 63;
  float m = -INFINITY, s = 0.f;
  for (int i = lane; i < NB1; i += 64) {
    float2 ps = part[lvl * NB1 + i];
    float Mn = fmaxf(m, ps.x);
    if (Mn > -INFINITY) {
      s = s * __expf(m - Mn) + ps.y * __expf(ps.x - Mn);
      m = Mn;
    }
  }
  #pragma unroll
  for (int off = 32; off; off >>= 1) {
    float mo = __shfl_xor(m, off);
    float so = __shfl_xor(s, off);
    float Mn = fmaxf(m, mo);
    if (Mn > -INFINITY) {
      s = s * __expf(m - Mn) + so * __expf(mo - Mn);
      m = Mn;
    }
  }
  if (lane == 0) stats[lvl] = make_float2(m, s);
}

// ---------------- pass 2: weights + fused output --------------------------------
__global__ __launch_bounds__(256) void k_pass2(Ptrs pt, const float* __restrict__ logits,
                                               const float2* __restrict__ stats,
                                               float* __restrict__ out, int N)
{
  const int lane = threadIdx.x & 63;
  const int wid  = threadIdx.x >> 6;
  float M[NLVL], Si[NLVL];
  #pragma unroll
  for (int l = 0; l < NLVL; l++) { float2 st = stats[l]; M[l] = st.x; Si[l] = 1.f / st.y; }

  const int gw = blockIdx.x * 4 + wid;
  const int nw = gridDim.x * 4;
  for (int n = gw; n < N; n += nw) {
    float wl[NLVL], t = 0.f;
    #pragma unroll
    for (int l = 0; l < NLVL; l++) {
      float e = __expf(logits[(size_t)l * N + n] - M[l]) * Si[l];  // softmax over batch
      wl[l] = e; t += e;
    }
    const float inv = 1.f / t;                 // normalize across levels per sample
    float4 acc = make_float4(0.f, 0.f, 0.f, 0.f);
    #pragma unroll
    for (int l = 0; l < NLVL; l++) {
      float4 pv = *reinterpret_cast<const float4*>(pt.p[l] + (size_t)n * DIM + lane * 4);
      float c = wl[l] * inv;
      acc.x += c * pv.x; acc.y += c * pv.y; acc.z += c * pv.z; acc.w += c * pv.w;
    }
    *reinterpret_cast<float4*>(out + (size_t)n * DIM + lane * 4) = acc;
  }
}

extern "C" void kernel_launch(void* const* d_in, const int* in_sizes, int n_in,
                              void* d_out, int out_size, void* d_ws, size_t ws_size,
                              hipStream_t stream)
{
  Ptrs pt;
  for (int l = 0; l < NLVL; l++) {
    pt.p[l] = (const float*)d_in[l];           // p3..p7
    pt.W[l] = (const float*)d_in[5 + 2 * l];   // W3,b3,W4,b4,...
    pt.b[l] = (const float*)d_in[6 + 2 * l];
  }
  const int N = in_sizes[0] / DIM;             // 100000

  char* ws = (char*)d_ws;
  size_t logits_bytes = ((size_t)NLVL * N * sizeof(float) + 255) & ~(size_t)255;
  float*  logits = (float*)ws;
  float2* part   = (float2*)(ws + logits_bytes);
  float2* stats  = part + NLVL * NB1;

  dim3 g1(NB1, NLVL);
  k_pass1 <<<g1,   256, 0, stream>>>(pt, logits, part, N);
  k_reduce<<<1,    320, 0, stream>>>(part, stats);
  k_pass2 <<<2048, 256, 0, stream>>>(pt, logits, stats, (float*)d_out, N);
}

// Round 2
// 219.233 us; speedup vs baseline: 1.0014x; 1.0014x over previous
//
#include <hip/hip_runtime.h>
#include <math.h>

#define DIM   256
#define NLVL  5
#define NB1   512    // pass1 blocks per level
#define NSB   64     // stats blocks per level

struct Ptrs {
  const float* p[NLVL];
  const float* W[NLVL];
  const float* b[NLVL];
};

// ---- pass 1: logits only. 8 rows per wave-iteration, combined exchange-reduce.
__global__ __launch_bounds__(256) void k_pass1(Ptrs pt, float* __restrict__ logits, int N)
{
  const int lvl  = blockIdx.y;
  const float* __restrict__ p = pt.p[lvl];
  const int lane = threadIdx.x & 63;
  const int wid  = threadIdx.x >> 6;
  const float4 wf  = *reinterpret_cast<const float4*>(pt.W[lvl] + lane * 4);
  const float bias = *pt.b[lvl];

  const int nchunk = N >> 3;                   // 12500 chunks of 8 rows
  const int gw = blockIdx.x * 4 + wid;
  const int nw = gridDim.x * 4;
  for (int c = gw; c < nchunk; c += nw) {
    const float* base = p + (size_t)c * 8 * DIM + lane * 4;
    float v[8];
    #pragma unroll
    for (int j = 0; j < 8; j++) {              // 8 independent 1KB wave-loads
      float4 pv = *reinterpret_cast<const float4*>(base + j * DIM);
      v[j] = pv.x * wf.x + pv.y * wf.y + pv.z * wf.z + pv.w * wf.w;
    }
    // exchange-combine: after masks 32,16,8 lane holds row ((lane>>3)&7)'s
    // partial summed over the 8 lanes sharing (lane&7).
    #pragma unroll
    for (int step = 0; step < 3; step++) {
      const int m    = 32 >> step;
      const int half = 4 >> step;
      #pragma unroll
      for (int j = 0; j < half; j++) {
        float send = (lane & m) ? v[j] : v[j + half];
        float keep = (lane & m) ? v[j + half] : v[j];
        v[j] = keep + __shfl_xor(send, m);
      }
    }
    float d = v[0];
    d += __shfl_xor(d, 4);
    d += __shfl_xor(d, 2);
    d += __shfl_xor(d, 1);
    if ((lane & 7) == 0)                       // lanes 0,8,..,56 -> 8 consecutive floats
      logits[(size_t)lvl * N + c * 8 + ((lane >> 3) & 7)] = d + bias;
  }
}

// ---- stats pass A: per-(level,block) online-softmax partials over logits (2 MB)
__global__ __launch_bounds__(256) void k_stats(const float* __restrict__ logits,
                                               float2* __restrict__ part, int N)
{
  const int lvl = blockIdx.y;
  const float* __restrict__ lg = logits + (size_t)lvl * N;
  float m = -INFINITY, s = 0.f;
  for (int i = blockIdx.x * 256 + threadIdx.x; i < N; i += NSB * 256) {
    float d  = lg[i];
    float Mn = fmaxf(m, d);
    s = s * __expf(m - Mn) + __expf(d - Mn);
    m = Mn;
  }
  const int lane = threadIdx.x & 63;
  const int wid  = threadIdx.x >> 6;
  #pragma unroll
  for (int off = 32; off; off >>= 1) {
    float mo = __shfl_xor(m, off), so = __shfl_xor(s, off);
    float Mn = fmaxf(m, mo);
    if (Mn > -INFINITY) { s = s * __expf(m - Mn) + so * __expf(mo - Mn); m = Mn; }
  }
  __shared__ float smM[4], smS[4];
  if (lane == 0) { smM[wid] = m; smS[wid] = s; }
  __syncthreads();
  if (threadIdx.x == 0) {
    float M = smM[0], S = smS[0];
    #pragma unroll
    for (int i = 1; i < 4; i++) {
      float Mn = fmaxf(M, smM[i]);
      if (Mn > -INFINITY) { S = S * __expf(M - Mn) + smS[i] * __expf(smM[i] - Mn); M = Mn; }
    }
    part[lvl * NSB + blockIdx.x] = make_float2(M, S);
  }
}

// ---- stats pass B: combine NSB partials per level -> (M, S)
__global__ __launch_bounds__(320) void k_reduce(const float2* __restrict__ part,
                                                float2* __restrict__ stats)
{
  const int lvl  = threadIdx.x >> 6;           // 5 waves, one per level
  const int lane = threadIdx.x & 63;
  float m = -INFINITY, s = 0.f;
  if (lane < NSB) { float2 ps = part[lvl * NSB + lane]; m = ps.x; s = ps.y; }
  #pragma unroll
  for (int off = 32; off; off >>= 1) {
    float mo = __shfl_xor(m, off), so = __shfl_xor(s, off);
    float Mn = fmaxf(m, mo);
    if (Mn > -INFINITY) { s = s * __expf(m - Mn) + so * __expf(mo - Mn); m = Mn; }
  }
  if (lane == 0) stats[lvl] = make_float2(m, s);
}

// ---- pass 2: weights + fused output
__global__ __launch_bounds__(256) void k_pass2(Ptrs pt, const float* __restrict__ logits,
                                               const float2* __restrict__ stats,
                                               float* __restrict__ out, int N)
{
  const int lane = threadIdx.x & 63;
  const int wid  = threadIdx.x >> 6;
  float M[NLVL], Si[NLVL];
  #pragma unroll
  for (int l = 0; l < NLVL; l++) { float2 st = stats[l]; M[l] = st.x; Si[l] = 1.f / st.y; }

  const int gw = blockIdx.x * 4 + wid;
  const int nw = gridDim.x * 4;
  for (int n = gw; n < N; n += nw) {
    float wl[NLVL], t = 0.f;
    #pragma unroll
    for (int l = 0; l < NLVL; l++) {
      float e = __expf(logits[(size_t)l * N + n] - M[l]) * Si[l];
      wl[l] = e; t += e;
    }
    const float inv = 1.f / t;
    float4 acc = make_float4(0.f, 0.f, 0.f, 0.f);
    #pragma unroll
    for (int l = 0; l < NLVL; l++) {
      float4 pv = *reinterpret_cast<const float4*>(pt.p[l] + (size_t)n * DIM + lane * 4);
      float c = wl[l] * inv;
      acc.x += c * pv.x; acc.y += c * pv.y; acc.z += c * pv.z; acc.w += c * pv.w;
    }
    *reinterpret_cast<float4*>(out + (size_t)n * DIM + lane * 4) = acc;
  }
}

extern "C" void kernel_launch(void* const* d_in, const int* in_sizes, int n_in,
                              void* d_out, int out_size, void* d_ws, size_t ws_size,
                              hipStream_t stream)
{
  Ptrs pt;
  for (int l = 0; l < NLVL; l++) {
    pt.p[l] = (const float*)d_in[l];
    pt.W[l] = (const float*)d_in[5 + 2 * l];
    pt.b[l] = (const float*)d_in[6 + 2 * l];
  }
  const int N = in_sizes[0] / DIM;             // 100000

  char* ws = (char*)d_ws;
  size_t logits_bytes = ((size_t)NLVL * N * sizeof(float) + 255) & ~(size_t)255;
  float*  logits = (float*)ws;
  float2* part   = (float2*)(ws + logits_bytes);
  float2* stats  = part + NLVL * NSB;

  k_pass1 <<<dim3(NB1, NLVL), 256, 0, stream>>>(pt, logits, N);
  k_stats <<<dim3(NSB, NLVL), 256, 0, stream>>>(logits, part, N);
  k_reduce<<<1,               320, 0, stream>>>(part, stats);
  k_pass2 <<<2048,            256, 0, stream>>>(pt, logits, stats, (float*)d_out, N);
}